// Round 14
// baseline (243.248 us; speedup 1.0000x reference)
//
#include <hip/hip_runtime.h>
#include <hip/hip_bf16.h>
#include <math.h>

#define HW   3136
#define NIMG 64
#define M_TOT (NIMG * HW)   // 200704

typedef __attribute__((ext_vector_type(8))) short bf16x8_t;
typedef __attribute__((ext_vector_type(4))) float f32x4_t;
typedef __bf16 bf16x2v __attribute__((ext_vector_type(2)));

__device__ __forceinline__ unsigned short f2bf(float f) {
  union { float f; unsigned u; } v; v.f = f;
  unsigned r = v.u + 0x7FFFu + ((v.u >> 16) & 1u);
  return (unsigned short)(r >> 16);
}
__device__ __forceinline__ float bf2f(unsigned short h) {
  union { unsigned u; float f; } v; v.u = ((unsigned)h) << 16;
  return v.f;
}

// packed bf16 pair dot: c += a.l*b.l + a.h*b.h  (v_dot2_f32_bf16)
__device__ __forceinline__ float dot2bf(unsigned a, unsigned b, float c) {
#if __has_builtin(__builtin_amdgcn_fdot2_f32_bf16)
  return __builtin_amdgcn_fdot2_f32_bf16(__builtin_bit_cast(bf16x2v, a),
                                         __builtin_bit_cast(bf16x2v, b), c, false);
#else
  return c + bf2f((unsigned short)(a & 0xffffu)) * bf2f((unsigned short)(b & 0xffffu))
           + bf2f((unsigned short)(a >> 16)) * bf2f((unsigned short)(b >> 16));
#endif
}

// ---------------- K0: swizzle weight [N][K] into MFMA B-fragment order ----
__global__ void k0_swz(const float* __restrict__ wsrc, unsigned short* __restrict__ bsw,
                       int N, int K) {
  int idx = blockIdx.x * 256 + threadIdx.x;
  int total = (N / 16) * (K / 32) * 64;
  if (idx >= total) return;
  int l  = idx & 63;
  int fi = idx >> 6;
  int KT = K / 32;
  int nt = fi / KT, kt = fi - nt * KT;
  int nn = nt * 16 + (l & 15);
  int kb = kt * 32 + (l >> 4) * 8;
  const float* src = wsrc + (size_t)nn * K + kb;
  unsigned short* dst = bsw + (size_t)idx * 8;
#pragma unroll
  for (int j = 0; j < 8; j++) dst[j] = f2bf(src[j]);
}

// ---------------- K0c: fold GRN beta through w2 into bias ---------------
__global__ void k0_b2p(const float* __restrict__ w2, const float* __restrict__ grnb,
                       const float* __restrict__ b2, float* __restrict__ b2p) {
  int c = blockIdx.x * blockDim.x + threadIdx.x;
  if (c >= 96) return;
  float s = b2[c];
  const float* wr = w2 + (size_t)c * 384;
  for (int f = 0; f < 384; f++) s += grnb[f] * wr[f];
  b2p[c] = s;
}

// ---------------- K0w: dwconv weights -> bf16, rows padded to 8 ---------
__global__ void k0w(const float* __restrict__ dww, unsigned short* __restrict__ wswz) {
  int i = blockIdx.x * 256 + threadIdx.x;   // over 96*56
  if (i >= 96 * 56) return;
  int ch = i / 56, rem = i - ch * 56, dy = rem >> 3, dx = rem & 7;
  wswz[i] = (dx < 7) ? f2bf(dww[ch * 49 + dy * 7 + dx]) : (unsigned short)0;
}

// ===== K12f: FUSED dwconv + transpose + LN + GEMM1 + GELU + gx2 =========
// r14: conv inner loop via v_dot2_f32_bf16 (packed, no unpack; 39 vs 77
// VALU/dy); staging indices shift-only; LN sums via dot2.
__global__ __launch_bounds__(256, 3) void k12f(
    const float* __restrict__ x, const unsigned short* __restrict__ wswz,
    const float* __restrict__ dwb, const float* __restrict__ lng,
    const float* __restrict__ lnb, const unsigned short* __restrict__ B1,
    const float* __restrict__ b1, unsigned char* __restrict__ y1f8,
    float* __restrict__ gx2) {
  __shared__ char smem[28928];
  float* lnp = (float*)smem;                                    // 768 B
  unsigned short* xsh = (unsigned short*)(smem + 768);          // [32] ch-stride 232 us, 14848 B
  unsigned short (*ts)[104] = (unsigned short(*)[104])(smem + 15616);  // 13312 B
  unsigned char* ytB = (unsigned char*)(smem + 768);            // [64][200] fp8, aliases xsh/ts

  const int t = threadIdx.x;
  const int bid = blockIdx.x;
  const int n = bid / 49;
  const int tile = bid - n * 49;
  const int tr = tile / 7, tc = tile - tr * 7;
  const int h0 = tr * 8, w0 = tc * 8;

  if (t < 192) lnp[t] = (t < 96) ? lng[t] : lnb[t - 96];

  // ---- conv: 3 chunks of 32 channels ----
  const int cch = t & 31, crow = t >> 5;        // compute mapping
  const int sch = t >> 3, sub = t & 7;          // staging mapping (shift-only)
  const bool colInt = (tc >= 1) && (tc <= 5);
  const bool rowInt = (tr >= 1) && (tr <= 5);
  for (int cc = 0; cc < 3; cc++) {
    const int c0 = cc * 32;
    if (cc) __syncthreads();
    // stage xsh[ch][14][16] bf16; thread covers ch=sch, 7 of 56 uint2 slots
    const float* xbase = x + (size_t)(n * 96 + c0 + sch) * HW;
    unsigned short* shbase = &xsh[sch * 232];
#pragma unroll
    for (int j = 0; j < 7; j++) {
      int pos = sub + j * 8;               // 0..55
      int r = pos >> 2, cq = pos & 3;      // shifts only
      int h = h0 + r - 3;
      int wb = w0 + cq * 4 - 3;
      const float* xb = xbase + h * 56 + wb;
      float4 v;
      if (rowInt && colInt) {
        v = *(const float4*)xb;
      } else {
        v = make_float4(0.f, 0.f, 0.f, 0.f);
        if ((unsigned)h < 56u) {
          if (colInt) {
            v = *(const float4*)xb;
          } else {
            if ((unsigned)(wb + 0) < 56u) v.x = xb[0];
            if ((unsigned)(wb + 1) < 56u) v.y = xb[1];
            if ((unsigned)(wb + 2) < 56u) v.z = xb[2];
            if ((unsigned)(wb + 3) < 56u) v.w = xb[3];
          }
        }
      }
      uint2 u;
      u.x = (unsigned)f2bf(v.x) | ((unsigned)f2bf(v.y) << 16);
      u.y = (unsigned)f2bf(v.z) | ((unsigned)f2bf(v.w) << 16);
      *(uint2*)(shbase + r * 16 + cq * 4) = u;
    }
    bf16x8_t wv[7];
#pragma unroll
    for (int dy = 0; dy < 7; dy++)
      wv[dy] = *(const bf16x8_t*)&wswz[(size_t)(c0 + cch) * 56 + dy * 8];
    const float bias = dwb[c0 + cch];
    __syncthreads();
    // conv compute via dot2: thread = row crow, cols 0..7, ch c0+cch
    float acc[8];
#pragma unroll
    for (int j = 0; j < 8; j++) acc[j] = bias;
#pragma unroll
    for (int dy = 0; dy < 7; dy++) {
      const unsigned* pr = (const unsigned*)&xsh[cch * 232 + (crow + dy) * 16];
      uint4 pa = *(const uint4*)pr;
      uint4 pb = *(const uint4*)(pr + 4);
      unsigned p[8] = {pa.x, pa.y, pa.z, pa.w, pb.x, pb.y, pb.z, pb.w};
      unsigned q[7];
#pragma unroll
      for (int i = 0; i < 7; i++) q[i] = (p[i] >> 16) | (p[i + 1] << 16);
      const unsigned* wu = (const unsigned*)&wv[dy];
#pragma unroll
      for (int j = 0; j < 8; j += 2) {
        int b = j >> 1;
        acc[j] = dot2bf(wu[3], p[b + 3],
                 dot2bf(wu[2], p[b + 2],
                 dot2bf(wu[1], p[b + 1],
                 dot2bf(wu[0], p[b + 0], acc[j]))));
        acc[j + 1] = dot2bf(wu[3], q[b + 3],
                     dot2bf(wu[2], q[b + 2],
                     dot2bf(wu[1], q[b + 1],
                     dot2bf(wu[0], q[b + 0], acc[j + 1]))));
      }
    }
#pragma unroll
    for (int j = 0; j < 8; j++)
      ts[crow * 8 + j][c0 + cch] = f2bf(acc[j]);
  }
  __syncthreads();

  // ---- LayerNorm: 4 threads per pixel; sums via dot2 ----
  {
    const int px = t >> 2, q = t & 3;
    const unsigned onebf = 0x3F803F80u;   // (1.0bf16, 1.0bf16)
    unsigned vu[12];
    float s = 0.f, ss = 0.f;
#pragma unroll
    for (int j = 0; j < 12; j++) {
      vu[j] = *(const unsigned*)&ts[px][q * 24 + j * 2];
      s  = dot2bf(vu[j], onebf, s);
      ss = dot2bf(vu[j], vu[j], ss);
    }
    s  += __shfl_xor(s, 1);  s  += __shfl_xor(s, 2);
    ss += __shfl_xor(ss, 1); ss += __shfl_xor(ss, 2);
    float mu  = s * (1.f / 96.f);
    float var = ss * (1.f / 96.f) - mu * mu;
    float rs  = rsqrtf(var + 1e-6f);
#pragma unroll
    for (int j = 0; j < 12; j++) {
      int ch = q * 24 + j * 2;
      float v0 = bf2f((unsigned short)(vu[j] & 0xffffu));
      float v1 = bf2f((unsigned short)(vu[j] >> 16));
      float o0 = (v0 - mu) * rs * lnp[ch] + lnp[96 + ch];
      float o1 = (v1 - mu) * rs * lnp[ch + 1] + lnp[96 + ch + 1];
      *(unsigned*)&ts[px][ch] = (unsigned)f2bf(o0) | ((unsigned)f2bf(o1) << 16);
    }
  }
  __syncthreads();
  // ---- A fragments from ts ----
  const int wv_ = t >> 6, l = t & 63;
  const int lg = l >> 4, lr = l & 15;
  bf16x8_t af[4][3];
#pragma unroll
  for (int mt = 0; mt < 4; mt++)
#pragma unroll
    for (int kt = 0; kt < 3; kt++)
      af[mt][kt] = *(const bf16x8_t*)&ts[mt * 16 + lr][kt * 32 + lg * 8];
  __syncthreads();   // ts dies; ytB (aliased) may be written

  // ---- GEMM1 + GELU + gx2, two half-feature passes; y1 -> fp8 ----
  for (int half = 0; half < 2; half++) {
    for (int i = 0; i < 3; i++) {
      const int ntl = wv_ * 3 + i;
      const int nt  = half * 12 + ntl;
      bf16x8_t bf[3];
#pragma unroll
      for (int kt = 0; kt < 3; kt++)
        bf[kt] = *(const bf16x8_t*)(B1 + ((size_t)(nt * 3 + kt) * 64 + l) * 8);
      f32x4_t acc[4];
#pragma unroll
      for (int mt = 0; mt < 4; mt++) {
        f32x4_t a = {0.f, 0.f, 0.f, 0.f};
#pragma unroll
        for (int kt = 0; kt < 3; kt++)
          a = __builtin_amdgcn_mfma_f32_16x16x32_bf16(af[mt][kt], bf[kt], a, 0, 0, 0);
        acc[mt] = a;
      }
      const int f0 = nt * 16, fl0 = ntl * 16;
      float bias = b1[f0 + lr];
      float s2 = 0.f;
#pragma unroll
      for (int mt = 0; mt < 4; mt++) {
#pragma unroll
        for (int r = 0; r < 4; r++) {
          float v = acc[mt][r] + bias;
          float sq = v * v;
          float pe = fmaf(sq, -0.10295294f, -2.3021183f);
          float e  = __builtin_amdgcn_exp2f(v * pe);
          float g  = v * __builtin_amdgcn_rcpf(1.f + e);
          s2 += g * g;
          unsigned p8 = (unsigned)__builtin_amdgcn_cvt_pk_fp8_f32(g, g, 0, false);
          ytB[(mt * 16 + lg * 4 + r) * 200 + fl0 + lr] = (unsigned char)p8;
        }
      }
      s2 += __shfl_xor(s2, 16);
      s2 += __shfl_xor(s2, 32);
      if (l < 16) atomicAdd(gx2 + n * 384 + f0 + l, s2);
    }
    __syncthreads();
#pragma unroll
    for (int it = 0; it < 6; it++) {
      int id = t + it * 256;               // 1536 = 4 mt * 6 ktl * 64 ll
      int mt = id / 384, ktl = (id >> 6) % 6, ll = id & 63;
      unsigned long long d =
        *(const unsigned long long*)&ytB[(mt * 16 + (ll & 15)) * 200 + ktl * 32 + (ll >> 4) * 8];
      *(unsigned long long*)(y1f8 +
        (((size_t)(bid * 4 + mt) * 12 + half * 6 + ktl) * 64 + ll) * 8) = d;
    }
    __syncthreads();
  }
}

// -------- K3: GRN coefficients + per-image scaled B2 fragments (fp8) ----
__global__ __launch_bounds__(256) void k3_coefB(
    const float* __restrict__ gx2, const float* __restrict__ grng,
    const unsigned short* __restrict__ B2, unsigned char* __restrict__ B2s8) {
  __shared__ float red[256];
  __shared__ float cf[384];
  const int n = blockIdx.x, t = threadIdx.x;
  float s = 0.f;
  for (int f = t; f < 384; f += 256) {
    float g = sqrtf(gx2[n * 384 + f]);
    cf[f] = g; s += g;
  }
  red[t] = s; __syncthreads();
  for (int o = 128; o > 0; o >>= 1) {
    if (t < o) red[t] += red[t + o];
    __syncthreads();
  }
  float inv = 1.f / (red[0] * (1.f / 384.f) + 1e-6f);
  for (int f = t; f < 384; f += 256)
    cf[f] = 1.f + grng[f] * cf[f] * inv;
  __syncthreads();
  unsigned char* dstn = B2s8 + (size_t)n * 36864;
  for (int i = t; i < 4608; i += 256) {
    int e0 = i * 8;
    int fi = e0 >> 9, ll = (e0 & 511) >> 3;
    int kb = (fi % 12) * 32 + (ll >> 4) * 8;
    uint4 w = *(const uint4*)(B2 + e0);
    const unsigned* wu = (const unsigned*)&w;
    float vv[8];
#pragma unroll
    for (int h = 0; h < 4; h++) {
      vv[h * 2 + 0] = bf2f((unsigned short)(wu[h] & 0xffffu)) * cf[kb + h * 2];
      vv[h * 2 + 1] = bf2f((unsigned short)(wu[h] >> 16)) * cf[kb + h * 2 + 1];
    }
    unsigned p0 = (unsigned)__builtin_amdgcn_cvt_pk_fp8_f32(vv[0], vv[1], 0, false);
    p0 = (unsigned)__builtin_amdgcn_cvt_pk_fp8_f32(vv[2], vv[3], p0, true);
    unsigned p1 = (unsigned)__builtin_amdgcn_cvt_pk_fp8_f32(vv[4], vv[5], 0, false);
    p1 = (unsigned)__builtin_amdgcn_cvt_pk_fp8_f32(vv[6], vv[7], p1, true);
    uint2 o; o.x = p0; o.y = p1;
    *(uint2*)(dstn + e0) = o;
  }
}

// ---------------- K4: fp8 GEMM2 (M x 96 x 384) + residual ---------------
__global__ __launch_bounds__(256) void k4_gemm2(
    const unsigned char* __restrict__ y1f8, const unsigned char* __restrict__ B2s8,
    const float* __restrict__ b2p, const float* __restrict__ x,
    float* __restrict__ out) {
  __shared__ float zt[96][68];
  const int t  = threadIdx.x;
  const int wv = t >> 6, l = t & 63;
  const int lg = l >> 4, lr = l & 15;
  const int bid = blockIdx.x;
  const int n = bid / 49;
  const int tile = bid - n * 49;
  const int tr = tile / 7, tc = tile - tr * 7;
  const unsigned char* Bn = B2s8 + (size_t)n * 36864;

  long af[12];
  const unsigned char* ap = y1f8 + ((size_t)(bid * 4 + wv) * 12) * 512 + l * 8;
#pragma unroll
  for (int kt = 0; kt < 12; kt++)
    af[kt] = *(const long*)(ap + kt * 512);

  f32x4_t acc[6];
#pragma unroll
  for (int i = 0; i < 6; i++) acc[i] = (f32x4_t){0.f, 0.f, 0.f, 0.f};
#pragma unroll
  for (int kt = 0; kt < 12; kt++) {
#pragma unroll
    for (int nt = 0; nt < 6; nt++) {
      long b = *(const long*)(Bn + ((size_t)(nt * 12 + kt) * 64 + l) * 8);
      acc[nt] = __builtin_amdgcn_mfma_f32_16x16x32_fp8_fp8(af[kt], b, acc[nt], 0, 0, 0);
    }
  }
#pragma unroll
  for (int nt = 0; nt < 6; nt++) {
    int c = nt * 16 + lr;
#pragma unroll
    for (int r = 0; r < 4; r++)
      zt[c][wv * 16 + lg * 4 + r] = acc[nt][r];
  }
  __syncthreads();
#pragma unroll
  for (int it = 0; it < 6; it++) {
    int id = t + it * 256;  // 1536 = 96 c * 16 quads
    int c = id >> 4, q = id & 15;
    int row = q >> 1, jq = (q & 1) * 4;
    float4 z = *(const float4*)&zt[c][row * 8 + jq];
    size_t base = ((size_t)(n * 96 + c)) * HW + (size_t)(tr * 8 + row) * 56 + tc * 8 + jq;
    float4 xv = *(const float4*)(x + base);
    float bp = b2p[c];
    float4 o;
    o.x = xv.x + z.x + bp;
    o.y = xv.y + z.y + bp;
    o.z = xv.z + z.z + bp;
    o.w = xv.w + z.w + bp;
    *(float4*)(out + base) = o;
  }
}

// ---------------- launch -----------------------------------------------
extern "C" void kernel_launch(void* const* d_in, const int* in_sizes, int n_in,
                              void* d_out, int out_size, void* d_ws, size_t ws_size,
                              hipStream_t stream) {
  const float* x    = (const float*)d_in[0];
  const float* dww  = (const float*)d_in[1];
  const float* dwb  = (const float*)d_in[2];
  const float* lng  = (const float*)d_in[3];
  const float* lnb  = (const float*)d_in[4];
  const float* w1   = (const float*)d_in[5];
  const float* b1   = (const float*)d_in[6];
  const float* grng = (const float*)d_in[7];
  const float* grnb = (const float*)d_in[8];
  const float* w2   = (const float*)d_in[9];
  const float* b2   = (const float*)d_in[10];
  float* out = (float*)d_out;

  char* ws = (char*)d_ws;
  size_t off = 0;
  auto alloc = [&](size_t bytes) {
    char* p = ws + off;
    off += (bytes + 255) & ~(size_t)255;
    return p;
  };
  unsigned char*  y1f8 = (unsigned char*)alloc((size_t)M_TOT * 384);      // fp8
  unsigned char*  B2s8 = (unsigned char*)alloc((size_t)64 * 36864);       // fp8
  unsigned short* B1sw = (unsigned short*)alloc((size_t)384 * 96 * 2);
  unsigned short* B2sw = (unsigned short*)alloc((size_t)96 * 384 * 2);
  unsigned short* wswz = (unsigned short*)alloc((size_t)96 * 56 * 2);
  float* gx2  = (float*)alloc((size_t)64 * 384 * 4);
  float* b2p  = (float*)alloc((size_t)96 * 4);
  if (off > ws_size) return;

  hipMemsetAsync(gx2, 0, 64 * 384 * 4, stream);
  k0_swz<<<18, 256, 0, stream>>>(w1, B1sw, 384, 96);
  k0_swz<<<18, 256, 0, stream>>>(w2, B2sw, 96, 384);
  k0_b2p<<<1, 128, 0, stream>>>(w2, grnb, b2, b2p);
  k0w<<<21, 256, 0, stream>>>(dww, wswz);
  k12f<<<3136, 256, 0, stream>>>(x, wswz, dwb, lng, lnb, B1sw, b1, y1f8, gx2);
  k3_coefB<<<64, 256, 0, stream>>>(gx2, grng, B2sw, B2s8);
  k4_gemm2<<<3136, 256, 0, stream>>>(y1f8, B2s8, b2p, x, out);
}

// Round 15
// 228.878 us; speedup vs baseline: 1.0628x; 1.0628x over previous
//
#include <hip/hip_runtime.h>
#include <hip/hip_bf16.h>
#include <math.h>

#define HW   3136
#define NIMG 64
#define M_TOT (NIMG * HW)   // 200704

typedef __attribute__((ext_vector_type(8))) short bf16x8_t;
typedef __attribute__((ext_vector_type(4))) float f32x4_t;
typedef __bf16 bf16x2v __attribute__((ext_vector_type(2)));

__device__ __forceinline__ unsigned short f2bf(float f) {
  union { float f; unsigned u; } v; v.f = f;
  unsigned r = v.u + 0x7FFFu + ((v.u >> 16) & 1u);
  return (unsigned short)(r >> 16);
}
__device__ __forceinline__ float bf2f(unsigned short h) {
  union { unsigned u; float f; } v; v.u = ((unsigned)h) << 16;
  return v.f;
}

// packed bf16 pair dot: c += a.l*b.l + a.h*b.h  (v_dot2_f32_bf16)
__device__ __forceinline__ float dot2bf(unsigned a, unsigned b, float c) {
#if __has_builtin(__builtin_amdgcn_fdot2_f32_bf16)
  return __builtin_amdgcn_fdot2_f32_bf16(__builtin_bit_cast(bf16x2v, a),
                                         __builtin_bit_cast(bf16x2v, b), c, false);
#else
  return c + bf2f((unsigned short)(a & 0xffffu)) * bf2f((unsigned short)(b & 0xffffu))
           + bf2f((unsigned short)(a >> 16)) * bf2f((unsigned short)(b >> 16));
#endif
}

// ---------------- K0: swizzle weight [N][K] into MFMA B-fragment order ----
__global__ void k0_swz(const float* __restrict__ wsrc, unsigned short* __restrict__ bsw,
                       int N, int K) {
  int idx = blockIdx.x * 256 + threadIdx.x;
  int total = (N / 16) * (K / 32) * 64;
  if (idx >= total) return;
  int l  = idx & 63;
  int fi = idx >> 6;
  int KT = K / 32;
  int nt = fi / KT, kt = fi - nt * KT;
  int nn = nt * 16 + (l & 15);
  int kb = kt * 32 + (l >> 4) * 8;
  const float* src = wsrc + (size_t)nn * K + kb;
  unsigned short* dst = bsw + (size_t)idx * 8;
#pragma unroll
  for (int j = 0; j < 8; j++) dst[j] = f2bf(src[j]);
}

// ---------------- K0c: fold GRN beta through w2 into bias ---------------
__global__ void k0_b2p(const float* __restrict__ w2, const float* __restrict__ grnb,
                       const float* __restrict__ b2, float* __restrict__ b2p) {
  int c = blockIdx.x * blockDim.x + threadIdx.x;
  if (c >= 96) return;
  float s = b2[c];
  const float* wr = w2 + (size_t)c * 384;
  for (int f = 0; f < 384; f++) s += grnb[f] * wr[f];
  b2p[c] = s;
}

// ---------------- K0w: dwconv weights -> bf16, rows padded to 8 ---------
__global__ void k0w(const float* __restrict__ dww, unsigned short* __restrict__ wswz) {
  int i = blockIdx.x * 256 + threadIdx.x;   // over 96*56
  if (i >= 96 * 56) return;
  int ch = i / 56, rem = i - ch * 56, dy = rem >> 3, dx = rem & 7;
  wswz[i] = (dx < 7) ? f2bf(dww[ch * 49 + dy * 7 + dx]) : (unsigned short)0;
}

// ===== K12f: FUSED dwconv + transpose + LN + GEMM1 + GELU + gx2 =========
// r15: async-stage split — ALL 21 conv staging loads (3 chunks x 7 float4)
// issued into registers before the first barrier; one vmcnt drain instead
// of 3 serial exposures. Staging mapping reverted to r13 (coalescing).
__global__ __launch_bounds__(256, 3) void k12f(
    const float* __restrict__ x, const unsigned short* __restrict__ wswz,
    const float* __restrict__ dwb, const float* __restrict__ lng,
    const float* __restrict__ lnb, const unsigned short* __restrict__ B1,
    const float* __restrict__ b1, unsigned char* __restrict__ y1f8,
    float* __restrict__ gx2) {
  __shared__ char smem[28928];
  float* lnp = (float*)smem;                                    // 768 B
  unsigned short* xsh = (unsigned short*)(smem + 768);          // [32] ch-stride 232 us, 14848 B
  unsigned short (*ts)[104] = (unsigned short(*)[104])(smem + 15616);  // 13312 B
  unsigned char* ytB = (unsigned char*)(smem + 768);            // [64][200] fp8, aliases xsh/ts

  const int t = threadIdx.x;
  const int bid = blockIdx.x;
  const int n = bid / 49;
  const int tile = bid - n * 49;
  const int tr = tile / 7, tc = tile - tr * 7;
  const int h0 = tr * 8, w0 = tc * 8;

  if (t < 192) lnp[t] = (t < 96) ? lng[t] : lnb[t - 96];

  const int cch = t & 31, crow = t >> 5;        // conv compute mapping
  const bool colInt = (tc >= 1) && (tc <= 5);
  const bool rowInt = (tr >= 1) && (tr <= 5);

  // ---- staging-slot geometry (r13 mapping; per-thread, 7 slots) ----
  int g_r[7], g_ch[7], g_wb[7];
  bool g_hok[7];
#pragma unroll
  for (int k = 0; k < 7; k++) {
    int i = t + k * 256;                 // < 1792
    int cq = i & 3;
    int rc = i >> 2;
    g_r[k] = rc % 14; g_ch[k] = rc / 14;
    g_wb[k] = w0 + cq * 4 - 3;
    g_hok[k] = (unsigned)(h0 + g_r[k] - 3) < 56u;
  }

  // ---- issue ALL 21 staging loads into registers (async-stage split) ----
  float4 raw[3][7];
#pragma unroll
  for (int cc = 0; cc < 3; cc++) {
#pragma unroll
    for (int k = 0; k < 7; k++) {
      const int h = h0 + g_r[k] - 3;
      const int wb = g_wb[k];
      const float* xb = x + (size_t)(n * 96 + cc * 32 + g_ch[k]) * HW + h * 56 + wb;
      float4 v;
      if (rowInt && colInt) {
        v = *(const float4*)xb;          // fully interior: branch-free
      } else {
        v = make_float4(0.f, 0.f, 0.f, 0.f);
        if (g_hok[k]) {
          if (colInt) {
            v = *(const float4*)xb;
          } else {
            if ((unsigned)(wb + 0) < 56u) v.x = xb[0];
            if ((unsigned)(wb + 1) < 56u) v.y = xb[1];
            if ((unsigned)(wb + 2) < 56u) v.z = xb[2];
            if ((unsigned)(wb + 3) < 56u) v.w = xb[3];
          }
        }
      }
      raw[cc][k] = v;
    }
  }

  // ---- conv: 3 chunks of 32 channels; LDS writes from registers ----
#pragma unroll
  for (int cc = 0; cc < 3; cc++) {
    const int c0 = cc * 32;
    if (cc) __syncthreads();             // prev chunk's compute reads done
#pragma unroll
    for (int k = 0; k < 7; k++) {
      float4 v = raw[cc][k];
      uint2 u;
      u.x = (unsigned)f2bf(v.x) | ((unsigned)f2bf(v.y) << 16);
      u.y = (unsigned)f2bf(v.z) | ((unsigned)f2bf(v.w) << 16);
      *(uint2*)&xsh[g_ch[k] * 232 + g_r[k] * 16 + (g_wb[k] - w0 + 3)] = u;  // cq*4
    }
    bf16x8_t wv[7];
#pragma unroll
    for (int dy = 0; dy < 7; dy++)
      wv[dy] = *(const bf16x8_t*)&wswz[(size_t)(c0 + cch) * 56 + dy * 8];
    const float bias = dwb[c0 + cch];
    __syncthreads();
    // conv compute via dot2: thread = row crow, cols 0..7, ch c0+cch
    float acc[8];
#pragma unroll
    for (int j = 0; j < 8; j++) acc[j] = bias;
#pragma unroll
    for (int dy = 0; dy < 7; dy++) {
      const unsigned* pr = (const unsigned*)&xsh[cch * 232 + (crow + dy) * 16];
      uint4 pa = *(const uint4*)pr;
      uint4 pb = *(const uint4*)(pr + 4);
      unsigned p[8] = {pa.x, pa.y, pa.z, pa.w, pb.x, pb.y, pb.z, pb.w};
      unsigned q[7];
#pragma unroll
      for (int i = 0; i < 7; i++) q[i] = (p[i] >> 16) | (p[i + 1] << 16);
      const unsigned* wu = (const unsigned*)&wv[dy];
#pragma unroll
      for (int j = 0; j < 8; j += 2) {
        int b = j >> 1;
        acc[j] = dot2bf(wu[3], p[b + 3],
                 dot2bf(wu[2], p[b + 2],
                 dot2bf(wu[1], p[b + 1],
                 dot2bf(wu[0], p[b + 0], acc[j]))));
        acc[j + 1] = dot2bf(wu[3], q[b + 3],
                     dot2bf(wu[2], q[b + 2],
                     dot2bf(wu[1], q[b + 1],
                     dot2bf(wu[0], q[b + 0], acc[j + 1]))));
      }
    }
#pragma unroll
    for (int j = 0; j < 8; j++)
      ts[crow * 8 + j][c0 + cch] = f2bf(acc[j]);
  }
  __syncthreads();

  // ---- LayerNorm: 4 threads per pixel; sums via dot2 ----
  {
    const int px = t >> 2, q = t & 3;
    const unsigned onebf = 0x3F803F80u;   // (1.0bf16, 1.0bf16)
    unsigned vu[12];
    float s = 0.f, ss = 0.f;
#pragma unroll
    for (int j = 0; j < 12; j++) {
      vu[j] = *(const unsigned*)&ts[px][q * 24 + j * 2];
      s  = dot2bf(vu[j], onebf, s);
      ss = dot2bf(vu[j], vu[j], ss);
    }
    s  += __shfl_xor(s, 1);  s  += __shfl_xor(s, 2);
    ss += __shfl_xor(ss, 1); ss += __shfl_xor(ss, 2);
    float mu  = s * (1.f / 96.f);
    float var = ss * (1.f / 96.f) - mu * mu;
    float rs  = rsqrtf(var + 1e-6f);
#pragma unroll
    for (int j = 0; j < 12; j++) {
      int ch = q * 24 + j * 2;
      float v0 = bf2f((unsigned short)(vu[j] & 0xffffu));
      float v1 = bf2f((unsigned short)(vu[j] >> 16));
      float o0 = (v0 - mu) * rs * lnp[ch] + lnp[96 + ch];
      float o1 = (v1 - mu) * rs * lnp[ch + 1] + lnp[96 + ch + 1];
      *(unsigned*)&ts[px][ch] = (unsigned)f2bf(o0) | ((unsigned)f2bf(o1) << 16);
    }
  }
  __syncthreads();
  // ---- A fragments from ts ----
  const int wv_ = t >> 6, l = t & 63;
  const int lg = l >> 4, lr = l & 15;
  bf16x8_t af[4][3];
#pragma unroll
  for (int mt = 0; mt < 4; mt++)
#pragma unroll
    for (int kt = 0; kt < 3; kt++)
      af[mt][kt] = *(const bf16x8_t*)&ts[mt * 16 + lr][kt * 32 + lg * 8];
  __syncthreads();   // ts dies; ytB (aliased) may be written

  // ---- GEMM1 + GELU + gx2, two half-feature passes; y1 -> fp8 ----
  for (int half = 0; half < 2; half++) {
    for (int i = 0; i < 3; i++) {
      const int ntl = wv_ * 3 + i;
      const int nt  = half * 12 + ntl;
      bf16x8_t bf[3];
#pragma unroll
      for (int kt = 0; kt < 3; kt++)
        bf[kt] = *(const bf16x8_t*)(B1 + ((size_t)(nt * 3 + kt) * 64 + l) * 8);
      f32x4_t acc[4];
#pragma unroll
      for (int mt = 0; mt < 4; mt++) {
        f32x4_t a = {0.f, 0.f, 0.f, 0.f};
#pragma unroll
        for (int kt = 0; kt < 3; kt++)
          a = __builtin_amdgcn_mfma_f32_16x16x32_bf16(af[mt][kt], bf[kt], a, 0, 0, 0);
        acc[mt] = a;
      }
      const int f0 = nt * 16, fl0 = ntl * 16;
      float bias = b1[f0 + lr];
      float s2 = 0.f;
#pragma unroll
      for (int mt = 0; mt < 4; mt++) {
#pragma unroll
        for (int r = 0; r < 4; r++) {
          float v = acc[mt][r] + bias;
          float sq = v * v;
          float pe = fmaf(sq, -0.10295294f, -2.3021183f);
          float e  = __builtin_amdgcn_exp2f(v * pe);
          float g  = v * __builtin_amdgcn_rcpf(1.f + e);
          s2 += g * g;
          unsigned p8 = (unsigned)__builtin_amdgcn_cvt_pk_fp8_f32(g, g, 0, false);
          ytB[(mt * 16 + lg * 4 + r) * 200 + fl0 + lr] = (unsigned char)p8;
        }
      }
      s2 += __shfl_xor(s2, 16);
      s2 += __shfl_xor(s2, 32);
      if (l < 16) atomicAdd(gx2 + n * 384 + f0 + l, s2);
    }
    __syncthreads();
#pragma unroll
    for (int it = 0; it < 6; it++) {
      int id = t + it * 256;               // 1536 = 4 mt * 6 ktl * 64 ll
      int mt = id / 384, ktl = (id >> 6) % 6, ll = id & 63;
      unsigned long long d =
        *(const unsigned long long*)&ytB[(mt * 16 + (ll & 15)) * 200 + ktl * 32 + (ll >> 4) * 8];
      *(unsigned long long*)(y1f8 +
        (((size_t)(bid * 4 + mt) * 12 + half * 6 + ktl) * 64 + ll) * 8) = d;
    }
    __syncthreads();
  }
}

// -------- K3: GRN coefficients + per-image scaled B2 fragments (fp8) ----
__global__ __launch_bounds__(256) void k3_coefB(
    const float* __restrict__ gx2, const float* __restrict__ grng,
    const unsigned short* __restrict__ B2, unsigned char* __restrict__ B2s8) {
  __shared__ float red[256];
  __shared__ float cf[384];
  const int n = blockIdx.x, t = threadIdx.x;
  float s = 0.f;
  for (int f = t; f < 384; f += 256) {
    float g = sqrtf(gx2[n * 384 + f]);
    cf[f] = g; s += g;
  }
  red[t] = s; __syncthreads();
  for (int o = 128; o > 0; o >>= 1) {
    if (t < o) red[t] += red[t + o];
    __syncthreads();
  }
  float inv = 1.f / (red[0] * (1.f / 384.f) + 1e-6f);
  for (int f = t; f < 384; f += 256)
    cf[f] = 1.f + grng[f] * cf[f] * inv;
  __syncthreads();
  unsigned char* dstn = B2s8 + (size_t)n * 36864;
  for (int i = t; i < 4608; i += 256) {
    int e0 = i * 8;
    int fi = e0 >> 9, ll = (e0 & 511) >> 3;
    int kb = (fi % 12) * 32 + (ll >> 4) * 8;
    uint4 w = *(const uint4*)(B2 + e0);
    const unsigned* wu = (const unsigned*)&w;
    float vv[8];
#pragma unroll
    for (int h = 0; h < 4; h++) {
      vv[h * 2 + 0] = bf2f((unsigned short)(wu[h] & 0xffffu)) * cf[kb + h * 2];
      vv[h * 2 + 1] = bf2f((unsigned short)(wu[h] >> 16)) * cf[kb + h * 2 + 1];
    }
    unsigned p0 = (unsigned)__builtin_amdgcn_cvt_pk_fp8_f32(vv[0], vv[1], 0, false);
    p0 = (unsigned)__builtin_amdgcn_cvt_pk_fp8_f32(vv[2], vv[3], p0, true);
    unsigned p1 = (unsigned)__builtin_amdgcn_cvt_pk_fp8_f32(vv[4], vv[5], 0, false);
    p1 = (unsigned)__builtin_amdgcn_cvt_pk_fp8_f32(vv[6], vv[7], p1, true);
    uint2 o; o.x = p0; o.y = p1;
    *(uint2*)(dstn + e0) = o;
  }
}

// ---------------- K4: fp8 GEMM2 (M x 96 x 384) + residual ---------------
__global__ __launch_bounds__(256) void k4_gemm2(
    const unsigned char* __restrict__ y1f8, const unsigned char* __restrict__ B2s8,
    const float* __restrict__ b2p, const float* __restrict__ x,
    float* __restrict__ out) {
  __shared__ float zt[96][68];
  const int t  = threadIdx.x;
  const int wv = t >> 6, l = t & 63;
  const int lg = l >> 4, lr = l & 15;
  const int bid = blockIdx.x;
  const int n = bid / 49;
  const int tile = bid - n * 49;
  const int tr = tile / 7, tc = tile - tr * 7;
  const unsigned char* Bn = B2s8 + (size_t)n * 36864;

  long af[12];
  const unsigned char* ap = y1f8 + ((size_t)(bid * 4 + wv) * 12) * 512 + l * 8;
#pragma unroll
  for (int kt = 0; kt < 12; kt++)
    af[kt] = *(const long*)(ap + kt * 512);

  f32x4_t acc[6];
#pragma unroll
  for (int i = 0; i < 6; i++) acc[i] = (f32x4_t){0.f, 0.f, 0.f, 0.f};
#pragma unroll
  for (int kt = 0; kt < 12; kt++) {
#pragma unroll
    for (int nt = 0; nt < 6; nt++) {
      long b = *(const long*)(Bn + ((size_t)(nt * 12 + kt) * 64 + l) * 8);
      acc[nt] = __builtin_amdgcn_mfma_f32_16x16x32_fp8_fp8(af[kt], b, acc[nt], 0, 0, 0);
    }
  }
#pragma unroll
  for (int nt = 0; nt < 6; nt++) {
    int c = nt * 16 + lr;
#pragma unroll
    for (int r = 0; r < 4; r++)
      zt[c][wv * 16 + lg * 4 + r] = acc[nt][r];
  }
  __syncthreads();
#pragma unroll
  for (int it = 0; it < 6; it++) {
    int id = t + it * 256;  // 1536 = 96 c * 16 quads
    int c = id >> 4, q = id & 15;
    int row = q >> 1, jq = (q & 1) * 4;
    float4 z = *(const float4*)&zt[c][row * 8 + jq];
    size_t base = ((size_t)(n * 96 + c)) * HW + (size_t)(tr * 8 + row) * 56 + tc * 8 + jq;
    float4 xv = *(const float4*)(x + base);
    float bp = b2p[c];
    float4 o;
    o.x = xv.x + z.x + bp;
    o.y = xv.y + z.y + bp;
    o.z = xv.z + z.z + bp;
    o.w = xv.w + z.w + bp;
    *(float4*)(out + base) = o;
  }
}

// ---------------- launch -----------------------------------------------
extern "C" void kernel_launch(void* const* d_in, const int* in_sizes, int n_in,
                              void* d_out, int out_size, void* d_ws, size_t ws_size,
                              hipStream_t stream) {
  const float* x    = (const float*)d_in[0];
  const float* dww  = (const float*)d_in[1];
  const float* dwb  = (const float*)d_in[2];
  const float* lng  = (const float*)d_in[3];
  const float* lnb  = (const float*)d_in[4];
  const float* w1   = (const float*)d_in[5];
  const float* b1   = (const float*)d_in[6];
  const float* grng = (const float*)d_in[7];
  const float* grnb = (const float*)d_in[8];
  const float* w2   = (const float*)d_in[9];
  const float* b2   = (const float*)d_in[10];
  float* out = (float*)d_out;

  char* ws = (char*)d_ws;
  size_t off = 0;
  auto alloc = [&](size_t bytes) {
    char* p = ws + off;
    off += (bytes + 255) & ~(size_t)255;
    return p;
  };
  unsigned char*  y1f8 = (unsigned char*)alloc((size_t)M_TOT * 384);      // fp8
  unsigned char*  B2s8 = (unsigned char*)alloc((size_t)64 * 36864);       // fp8
  unsigned short* B1sw = (unsigned short*)alloc((size_t)384 * 96 * 2);
  unsigned short* B2sw = (unsigned short*)alloc((size_t)96 * 384 * 2);
  unsigned short* wswz = (unsigned short*)alloc((size_t)96 * 56 * 2);
  float* gx2  = (float*)alloc((size_t)64 * 384 * 4);
  float* b2p  = (float*)alloc((size_t)96 * 4);
  if (off > ws_size) return;

  hipMemsetAsync(gx2, 0, 64 * 384 * 4, stream);
  k0_swz<<<18, 256, 0, stream>>>(w1, B1sw, 384, 96);
  k0_swz<<<18, 256, 0, stream>>>(w2, B2sw, 96, 384);
  k0_b2p<<<1, 128, 0, stream>>>(w2, grnb, b2, b2p);
  k0w<<<21, 256, 0, stream>>>(dww, wswz);
  k12f<<<3136, 256, 0, stream>>>(x, wswz, dwb, lng, lnb, B1sw, b1, y1f8, gx2);
  k3_coefB<<<64, 256, 0, stream>>>(gx2, grng, B2sw, B2s8);
  k4_gemm2<<<3136, 256, 0, stream>>>(y1f8, B2s8, b2p, x, out);
}

// Round 16
// 182.877 us; speedup vs baseline: 1.3301x; 1.2515x over previous
//
#include <hip/hip_runtime.h>
#include <hip/hip_bf16.h>
#include <math.h>

#define HW   3136
#define NIMG 64
#define M_TOT (NIMG * HW)   // 200704

typedef __attribute__((ext_vector_type(8))) short bf16x8_t;
typedef __attribute__((ext_vector_type(4))) float f32x4_t;
typedef __bf16 bf16x2v __attribute__((ext_vector_type(2)));

__device__ __forceinline__ unsigned short f2bf(float f) {
  union { float f; unsigned u; } v; v.f = f;
  unsigned r = v.u + 0x7FFFu + ((v.u >> 16) & 1u);
  return (unsigned short)(r >> 16);
}
__device__ __forceinline__ float bf2f(unsigned short h) {
  union { unsigned u; float f; } v; v.u = ((unsigned)h) << 16;
  return v.f;
}

// packed bf16 pair dot: c += a.l*b.l + a.h*b.h  (v_dot2_f32_bf16)
__device__ __forceinline__ float dot2bf(unsigned a, unsigned b, float c) {
#if __has_builtin(__builtin_amdgcn_fdot2_f32_bf16)
  return __builtin_amdgcn_fdot2_f32_bf16(__builtin_bit_cast(bf16x2v, a),
                                         __builtin_bit_cast(bf16x2v, b), c, false);
#else
  return c + bf2f((unsigned short)(a & 0xffffu)) * bf2f((unsigned short)(b & 0xffffu))
           + bf2f((unsigned short)(a >> 16)) * bf2f((unsigned short)(b >> 16));
#endif
}

// XCD-aware block swizzle: 3136 = 8 XCDs * 392. XCD j gets contiguous work
// [j*392, (j+1)*392) = whole images -> halo re-reads hit that XCD's L2.
__device__ __forceinline__ int xcd_swz(int bid0) {
  return ((bid0 & 7) * 392) + (bid0 >> 3);
}

// ---------------- K0: swizzle weight [N][K] into MFMA B-fragment order ----
__global__ void k0_swz(const float* __restrict__ wsrc, unsigned short* __restrict__ bsw,
                       int N, int K) {
  int idx = blockIdx.x * 256 + threadIdx.x;
  int total = (N / 16) * (K / 32) * 64;
  if (idx >= total) return;
  int l  = idx & 63;
  int fi = idx >> 6;
  int KT = K / 32;
  int nt = fi / KT, kt = fi - nt * KT;
  int nn = nt * 16 + (l & 15);
  int kb = kt * 32 + (l >> 4) * 8;
  const float* src = wsrc + (size_t)nn * K + kb;
  unsigned short* dst = bsw + (size_t)idx * 8;
#pragma unroll
  for (int j = 0; j < 8; j++) dst[j] = f2bf(src[j]);
}

// ---------------- K0c: fold GRN beta through w2 into bias ---------------
__global__ void k0_b2p(const float* __restrict__ w2, const float* __restrict__ grnb,
                       const float* __restrict__ b2, float* __restrict__ b2p) {
  int c = blockIdx.x * blockDim.x + threadIdx.x;
  if (c >= 96) return;
  float s = b2[c];
  const float* wr = w2 + (size_t)c * 384;
  for (int f = 0; f < 384; f++) s += grnb[f] * wr[f];
  b2p[c] = s;
}

// ---------------- K0w: dwconv weights -> bf16, rows padded to 8 ---------
__global__ void k0w(const float* __restrict__ dww, unsigned short* __restrict__ wswz) {
  int i = blockIdx.x * 256 + threadIdx.x;   // over 96*56
  if (i >= 96 * 56) return;
  int ch = i / 56, rem = i - ch * 56, dy = rem >> 3, dx = rem & 7;
  wswz[i] = (dx < 7) ? f2bf(dww[ch * 49 + dy * 7 + dx]) : (unsigned short)0;
}

// ===== K12f: FUSED dwconv + transpose + LN + GEMM1 + GELU + gx2 =========
// r16: XCD-aware block swizzle (halo re-reads -> L2 hits).
__global__ __launch_bounds__(256, 3) void k12f(
    const float* __restrict__ x, const unsigned short* __restrict__ wswz,
    const float* __restrict__ dwb, const float* __restrict__ lng,
    const float* __restrict__ lnb, const unsigned short* __restrict__ B1,
    const float* __restrict__ b1, unsigned char* __restrict__ y1f8,
    float* __restrict__ gx2) {
  __shared__ char smem[28928];
  float* lnp = (float*)smem;                                    // 768 B
  unsigned short* xsh = (unsigned short*)(smem + 768);          // [32] ch-stride 232 us, 14848 B
  unsigned short (*ts)[104] = (unsigned short(*)[104])(smem + 15616);  // 13312 B
  unsigned char* ytB = (unsigned char*)(smem + 768);            // [64][200] fp8, aliases xsh/ts

  const int t = threadIdx.x;
  const int bid = xcd_swz(blockIdx.x);
  const int n = bid / 49;
  const int tile = bid - n * 49;
  const int tr = tile / 7, tc = tile - tr * 7;
  const int h0 = tr * 8, w0 = tc * 8;

  if (t < 192) lnp[t] = (t < 96) ? lng[t] : lnb[t - 96];

  const int cch = t & 31, crow = t >> 5;        // conv compute mapping
  const bool colInt = (tc >= 1) && (tc <= 5);
  const bool rowInt = (tr >= 1) && (tr <= 5);

  // ---- staging-slot geometry (per-thread, 7 slots) ----
  int g_r[7], g_ch[7], g_wb[7];
  bool g_hok[7];
#pragma unroll
  for (int k = 0; k < 7; k++) {
    int i = t + k * 256;                 // < 1792
    int cq = i & 3;
    int rc = i >> 2;
    g_r[k] = rc % 14; g_ch[k] = rc / 14;
    g_wb[k] = w0 + cq * 4 - 3;
    g_hok[k] = (unsigned)(h0 + g_r[k] - 3) < 56u;
  }

  // ---- issue ALL 21 staging loads into registers ----
  float4 raw[3][7];
#pragma unroll
  for (int cc = 0; cc < 3; cc++) {
#pragma unroll
    for (int k = 0; k < 7; k++) {
      const int h = h0 + g_r[k] - 3;
      const int wb = g_wb[k];
      const float* xb = x + (size_t)(n * 96 + cc * 32 + g_ch[k]) * HW + h * 56 + wb;
      float4 v;
      if (rowInt && colInt) {
        v = *(const float4*)xb;          // fully interior: branch-free
      } else {
        v = make_float4(0.f, 0.f, 0.f, 0.f);
        if (g_hok[k]) {
          if (colInt) {
            v = *(const float4*)xb;
          } else {
            if ((unsigned)(wb + 0) < 56u) v.x = xb[0];
            if ((unsigned)(wb + 1) < 56u) v.y = xb[1];
            if ((unsigned)(wb + 2) < 56u) v.z = xb[2];
            if ((unsigned)(wb + 3) < 56u) v.w = xb[3];
          }
        }
      }
      raw[cc][k] = v;
    }
  }

  // ---- conv: 3 chunks of 32 channels; LDS writes from registers ----
#pragma unroll
  for (int cc = 0; cc < 3; cc++) {
    const int c0 = cc * 32;
    if (cc) __syncthreads();             // prev chunk's compute reads done
#pragma unroll
    for (int k = 0; k < 7; k++) {
      float4 v = raw[cc][k];
      uint2 u;
      u.x = (unsigned)f2bf(v.x) | ((unsigned)f2bf(v.y) << 16);
      u.y = (unsigned)f2bf(v.z) | ((unsigned)f2bf(v.w) << 16);
      *(uint2*)&xsh[g_ch[k] * 232 + g_r[k] * 16 + (g_wb[k] - w0 + 3)] = u;  // cq*4
    }
    bf16x8_t wv[7];
#pragma unroll
    for (int dy = 0; dy < 7; dy++)
      wv[dy] = *(const bf16x8_t*)&wswz[(size_t)(c0 + cch) * 56 + dy * 8];
    const float bias = dwb[c0 + cch];
    __syncthreads();
    // conv compute via dot2: thread = row crow, cols 0..7, ch c0+cch
    float acc[8];
#pragma unroll
    for (int j = 0; j < 8; j++) acc[j] = bias;
#pragma unroll
    for (int dy = 0; dy < 7; dy++) {
      const unsigned* pr = (const unsigned*)&xsh[cch * 232 + (crow + dy) * 16];
      uint4 pa = *(const uint4*)pr;
      uint4 pb = *(const uint4*)(pr + 4);
      unsigned p[8] = {pa.x, pa.y, pa.z, pa.w, pb.x, pb.y, pb.z, pb.w};
      unsigned q[7];
#pragma unroll
      for (int i = 0; i < 7; i++) q[i] = (p[i] >> 16) | (p[i + 1] << 16);
      const unsigned* wu = (const unsigned*)&wv[dy];
#pragma unroll
      for (int j = 0; j < 8; j += 2) {
        int b = j >> 1;
        acc[j] = dot2bf(wu[3], p[b + 3],
                 dot2bf(wu[2], p[b + 2],
                 dot2bf(wu[1], p[b + 1],
                 dot2bf(wu[0], p[b + 0], acc[j]))));
        acc[j + 1] = dot2bf(wu[3], q[b + 3],
                     dot2bf(wu[2], q[b + 2],
                     dot2bf(wu[1], q[b + 1],
                     dot2bf(wu[0], q[b + 0], acc[j + 1]))));
      }
    }
#pragma unroll
    for (int j = 0; j < 8; j++)
      ts[crow * 8 + j][c0 + cch] = f2bf(acc[j]);
  }
  __syncthreads();

  // ---- LayerNorm: 4 threads per pixel; sums via dot2 ----
  {
    const int px = t >> 2, q = t & 3;
    const unsigned onebf = 0x3F803F80u;   // (1.0bf16, 1.0bf16)
    unsigned vu[12];
    float s = 0.f, ss = 0.f;
#pragma unroll
    for (int j = 0; j < 12; j++) {
      vu[j] = *(const unsigned*)&ts[px][q * 24 + j * 2];
      s  = dot2bf(vu[j], onebf, s);
      ss = dot2bf(vu[j], vu[j], ss);
    }
    s  += __shfl_xor(s, 1);  s  += __shfl_xor(s, 2);
    ss += __shfl_xor(ss, 1); ss += __shfl_xor(ss, 2);
    float mu  = s * (1.f / 96.f);
    float var = ss * (1.f / 96.f) - mu * mu;
    float rs  = rsqrtf(var + 1e-6f);
#pragma unroll
    for (int j = 0; j < 12; j++) {
      int ch = q * 24 + j * 2;
      float v0 = bf2f((unsigned short)(vu[j] & 0xffffu));
      float v1 = bf2f((unsigned short)(vu[j] >> 16));
      float o0 = (v0 - mu) * rs * lnp[ch] + lnp[96 + ch];
      float o1 = (v1 - mu) * rs * lnp[ch + 1] + lnp[96 + ch + 1];
      *(unsigned*)&ts[px][ch] = (unsigned)f2bf(o0) | ((unsigned)f2bf(o1) << 16);
    }
  }
  __syncthreads();
  // ---- A fragments from ts ----
  const int wv_ = t >> 6, l = t & 63;
  const int lg = l >> 4, lr = l & 15;
  bf16x8_t af[4][3];
#pragma unroll
  for (int mt = 0; mt < 4; mt++)
#pragma unroll
    for (int kt = 0; kt < 3; kt++)
      af[mt][kt] = *(const bf16x8_t*)&ts[mt * 16 + lr][kt * 32 + lg * 8];
  __syncthreads();   // ts dies; ytB (aliased) may be written

  // ---- GEMM1 + GELU + gx2, two half-feature passes; y1 -> fp8 ----
  for (int half = 0; half < 2; half++) {
    for (int i = 0; i < 3; i++) {
      const int ntl = wv_ * 3 + i;
      const int nt  = half * 12 + ntl;
      bf16x8_t bf[3];
#pragma unroll
      for (int kt = 0; kt < 3; kt++)
        bf[kt] = *(const bf16x8_t*)(B1 + ((size_t)(nt * 3 + kt) * 64 + l) * 8);
      f32x4_t acc[4];
#pragma unroll
      for (int mt = 0; mt < 4; mt++) {
        f32x4_t a = {0.f, 0.f, 0.f, 0.f};
#pragma unroll
        for (int kt = 0; kt < 3; kt++)
          a = __builtin_amdgcn_mfma_f32_16x16x32_bf16(af[mt][kt], bf[kt], a, 0, 0, 0);
        acc[mt] = a;
      }
      const int f0 = nt * 16, fl0 = ntl * 16;
      float bias = b1[f0 + lr];
      float s2 = 0.f;
#pragma unroll
      for (int mt = 0; mt < 4; mt++) {
#pragma unroll
        for (int r = 0; r < 4; r++) {
          float v = acc[mt][r] + bias;
          float sq = v * v;
          float pe = fmaf(sq, -0.10295294f, -2.3021183f);
          float e  = __builtin_amdgcn_exp2f(v * pe);
          float g  = v * __builtin_amdgcn_rcpf(1.f + e);
          s2 += g * g;
          unsigned p8 = (unsigned)__builtin_amdgcn_cvt_pk_fp8_f32(g, g, 0, false);
          ytB[(mt * 16 + lg * 4 + r) * 200 + fl0 + lr] = (unsigned char)p8;
        }
      }
      s2 += __shfl_xor(s2, 16);
      s2 += __shfl_xor(s2, 32);
      if (l < 16) atomicAdd(gx2 + n * 384 + f0 + l, s2);
    }
    __syncthreads();
#pragma unroll
    for (int it = 0; it < 6; it++) {
      int id = t + it * 256;               // 1536 = 4 mt * 6 ktl * 64 ll
      int mt = id / 384, ktl = (id >> 6) % 6, ll = id & 63;
      unsigned long long d =
        *(const unsigned long long*)&ytB[(mt * 16 + (ll & 15)) * 200 + ktl * 32 + (ll >> 4) * 8];
      *(unsigned long long*)(y1f8 +
        (((size_t)(bid * 4 + mt) * 12 + half * 6 + ktl) * 64 + ll) * 8) = d;
    }
    __syncthreads();
  }
}

// -------- K3: GRN coefficients + per-image scaled B2 fragments (fp8) ----
__global__ __launch_bounds__(256) void k3_coefB(
    const float* __restrict__ gx2, const float* __restrict__ grng,
    const unsigned short* __restrict__ B2, unsigned char* __restrict__ B2s8) {
  __shared__ float red[256];
  __shared__ float cf[384];
  const int n = blockIdx.x, t = threadIdx.x;
  float s = 0.f;
  for (int f = t; f < 384; f += 256) {
    float g = sqrtf(gx2[n * 384 + f]);
    cf[f] = g; s += g;
  }
  red[t] = s; __syncthreads();
  for (int o = 128; o > 0; o >>= 1) {
    if (t < o) red[t] += red[t + o];
    __syncthreads();
  }
  float inv = 1.f / (red[0] * (1.f / 384.f) + 1e-6f);
  for (int f = t; f < 384; f += 256)
    cf[f] = 1.f + grng[f] * cf[f] * inv;
  __syncthreads();
  unsigned char* dstn = B2s8 + (size_t)n * 36864;
  for (int i = t; i < 4608; i += 256) {
    int e0 = i * 8;
    int fi = e0 >> 9, ll = (e0 & 511) >> 3;
    int kb = (fi % 12) * 32 + (ll >> 4) * 8;
    uint4 w = *(const uint4*)(B2 + e0);
    const unsigned* wu = (const unsigned*)&w;
    float vv[8];
#pragma unroll
    for (int h = 0; h < 4; h++) {
      vv[h * 2 + 0] = bf2f((unsigned short)(wu[h] & 0xffffu)) * cf[kb + h * 2];
      vv[h * 2 + 1] = bf2f((unsigned short)(wu[h] >> 16)) * cf[kb + h * 2 + 1];
    }
    unsigned p0 = (unsigned)__builtin_amdgcn_cvt_pk_fp8_f32(vv[0], vv[1], 0, false);
    p0 = (unsigned)__builtin_amdgcn_cvt_pk_fp8_f32(vv[2], vv[3], p0, true);
    unsigned p1 = (unsigned)__builtin_amdgcn_cvt_pk_fp8_f32(vv[4], vv[5], 0, false);
    p1 = (unsigned)__builtin_amdgcn_cvt_pk_fp8_f32(vv[6], vv[7], p1, true);
    uint2 o; o.x = p0; o.y = p1;
    *(uint2*)(dstn + e0) = o;
  }
}

// ---------------- K4: fp8 GEMM2 (M x 96 x 384) + residual ---------------
// Same XCD swizzle as k12f (y1f8 storage layout is f(wid) on both sides).
__global__ __launch_bounds__(256) void k4_gemm2(
    const unsigned char* __restrict__ y1f8, const unsigned char* __restrict__ B2s8,
    const float* __restrict__ b2p, const float* __restrict__ x,
    float* __restrict__ out) {
  __shared__ float zt[96][68];
  const int t  = threadIdx.x;
  const int wv = t >> 6, l = t & 63;
  const int lg = l >> 4, lr = l & 15;
  const int bid = xcd_swz(blockIdx.x);
  const int n = bid / 49;
  const int tile = bid - n * 49;
  const int tr = tile / 7, tc = tile - tr * 7;
  const unsigned char* Bn = B2s8 + (size_t)n * 36864;

  long af[12];
  const unsigned char* ap = y1f8 + ((size_t)(bid * 4 + wv) * 12) * 512 + l * 8;
#pragma unroll
  for (int kt = 0; kt < 12; kt++)
    af[kt] = *(const long*)(ap + kt * 512);

  f32x4_t acc[6];
#pragma unroll
  for (int i = 0; i < 6; i++) acc[i] = (f32x4_t){0.f, 0.f, 0.f, 0.f};
#pragma unroll
  for (int kt = 0; kt < 12; kt++) {
#pragma unroll
    for (int nt = 0; nt < 6; nt++) {
      long b = *(const long*)(Bn + ((size_t)(nt * 12 + kt) * 64 + l) * 8);
      acc[nt] = __builtin_amdgcn_mfma_f32_16x16x32_fp8_fp8(af[kt], b, acc[nt], 0, 0, 0);
    }
  }
#pragma unroll
  for (int nt = 0; nt < 6; nt++) {
    int c = nt * 16 + lr;
#pragma unroll
    for (int r = 0; r < 4; r++)
      zt[c][wv * 16 + lg * 4 + r] = acc[nt][r];
  }
  __syncthreads();
#pragma unroll
  for (int it = 0; it < 6; it++) {
    int id = t + it * 256;  // 1536 = 96 c * 16 quads
    int c = id >> 4, q = id & 15;
    int row = q >> 1, jq = (q & 1) * 4;
    float4 z = *(const float4*)&zt[c][row * 8 + jq];
    size_t base = ((size_t)(n * 96 + c)) * HW + (size_t)(tr * 8 + row) * 56 + tc * 8 + jq;
    float4 xv = *(const float4*)(x + base);
    float bp = b2p[c];
    float4 o;
    o.x = xv.x + z.x + bp;
    o.y = xv.y + z.y + bp;
    o.z = xv.z + z.z + bp;
    o.w = xv.w + z.w + bp;
    *(float4*)(out + base) = o;
  }
}

// ---------------- launch -----------------------------------------------
extern "C" void kernel_launch(void* const* d_in, const int* in_sizes, int n_in,
                              void* d_out, int out_size, void* d_ws, size_t ws_size,
                              hipStream_t stream) {
  const float* x    = (const float*)d_in[0];
  const float* dww  = (const float*)d_in[1];
  const float* dwb  = (const float*)d_in[2];
  const float* lng  = (const float*)d_in[3];
  const float* lnb  = (const float*)d_in[4];
  const float* w1   = (const float*)d_in[5];
  const float* b1   = (const float*)d_in[6];
  const float* grng = (const float*)d_in[7];
  const float* grnb = (const float*)d_in[8];
  const float* w2   = (const float*)d_in[9];
  const float* b2   = (const float*)d_in[10];
  float* out = (float*)d_out;

  char* ws = (char*)d_ws;
  size_t off = 0;
  auto alloc = [&](size_t bytes) {
    char* p = ws + off;
    off += (bytes + 255) & ~(size_t)255;
    return p;
  };
  unsigned char*  y1f8 = (unsigned char*)alloc((size_t)M_TOT * 384);      // fp8
  unsigned char*  B2s8 = (unsigned char*)alloc((size_t)64 * 36864);       // fp8
  unsigned short* B1sw = (unsigned short*)alloc((size_t)384 * 96 * 2);
  unsigned short* B2sw = (unsigned short*)alloc((size_t)96 * 384 * 2);
  unsigned short* wswz = (unsigned short*)alloc((size_t)96 * 56 * 2);
  float* gx2  = (float*)alloc((size_t)64 * 384 * 4);
  float* b2p  = (float*)alloc((size_t)96 * 4);
  if (off > ws_size) return;

  hipMemsetAsync(gx2, 0, 64 * 384 * 4, stream);
  k0_swz<<<18, 256, 0, stream>>>(w1, B1sw, 384, 96);
  k0_swz<<<18, 256, 0, stream>>>(w2, B2sw, 96, 384);
  k0_b2p<<<1, 128, 0, stream>>>(w2, grnb, b2, b2p);
  k0w<<<21, 256, 0, stream>>>(dww, wswz);
  k12f<<<3136, 256, 0, stream>>>(x, wswz, dwb, lng, lnb, B1sw, b1, y1f8, gx2);
  k3_coefB<<<64, 256, 0, stream>>>(gx2, grng, B2sw, B2s8);
  k4_gemm2<<<3136, 256, 0, stream>>>(y1f8, B2s8, b2p, x, out);
}